// Round 6
// baseline (575.992 us; speedup 1.0000x reference)
//
#include <hip/hip_runtime.h>
#include <stdint.h>

// ---- Problem constants ----
// B=8192, IN=2048, OUT=2048, G=4.  K_total = 4096 (x-half then h-half).
// gates[b][g][o] = sum_k x[b][k]*Wi[g][k][o] + bi[g][o] + sum_k h[b][k]*Wh[g][k][o] + bh[g][o]
// next_c = sig(g1)*prev_c + sig(g0)*sig(g2);  next_h = sig(g3) + tanh(next_c)
// d_out = [next_h (8192*2048 f32)] ++ [next_c (8192*2048 f32)]

#define SZ_ELEMS 16777216
#define HALF_OUT 16777216

typedef __attribute__((ext_vector_type(8))) short bf16x8;
typedef __attribute__((ext_vector_type(4))) float f32x4;
typedef __attribute__((ext_vector_type(8))) unsigned short u16x8;

__device__ __forceinline__ unsigned short f2bf(float f) {
  unsigned int u = __float_as_uint(f);
  u += 0x7FFFu + ((u >> 16) & 1u);
  return (unsigned short)(u >> 16);
}

__device__ __forceinline__ void async16(const void* g, void* l) {
  __builtin_amdgcn_global_load_lds(
      (const __attribute__((address_space(1))) void*)g,
      (__attribute__((address_space(3))) void*)l, 16, 0, 0);
}

__device__ __forceinline__ float sigm(float x) { return 1.f / (1.f + __expf(-x)); }

// ---------------- f32 -> bf16 elementwise convert ----------------
__global__ void cvt_bf16_kernel(const float* __restrict__ src,
                                unsigned short* __restrict__ dst, int n4) {
  int i = blockIdx.x * blockDim.x + threadIdx.x;
  int stride = gridDim.x * blockDim.x;
  for (; i < n4; i += stride) {
    float4 v = reinterpret_cast<const float4*>(src)[i];
    ushort4 o;
    o.x = f2bf(v.x); o.y = f2bf(v.y); o.z = f2bf(v.z); o.w = f2bf(v.w);
    reinterpret_cast<ushort4*>(dst)[i] = o;
  }
}

// ---------------- W [g][k][o] f32  ->  Wt [g][o][k] bf16 ----------------
__global__ void transpose_w_kernel(const float* __restrict__ Wi, const float* __restrict__ Wh,
                                   unsigned short* __restrict__ Wit, unsigned short* __restrict__ Wht) {
  __shared__ float tile[64][65];
  const int tk = blockIdx.x, to = blockIdx.y, gz = blockIdx.z;
  const float* W = (gz < 4 ? Wi : Wh) + (size_t)(gz & 3) * 4194304;
  unsigned short* Wt = (gz < 4 ? Wit : Wht) + (size_t)(gz & 3) * 4194304;
  const int t = threadIdx.x;
  const int o = t & 63, kr = t >> 6;
#pragma unroll
  for (int p = 0; p < 16; ++p) {
    int k = p * 4 + kr;
    tile[k][o] = W[(size_t)(tk * 64 + k) * 2048 + to * 64 + o];
  }
  __syncthreads();
#pragma unroll
  for (int p = 0; p < 2; ++p) {
    int idx = p * 256 + t;
    int orow = idx >> 3, k0 = (idx & 7) * 8;
    u16x8 v;
#pragma unroll
    for (int i = 0; i < 8; ++i) v[i] = f2bf(tile[k0 + i][orow]);
    *reinterpret_cast<u16x8*>(&Wt[(size_t)(to * 64 + orow) * 2048 + tk * 64 + k0]) = v;
  }
}

// ---------------- fused GEMM (4 gates) + LSTM epilogue, 8-phase, 2 blocks/CU ----------------
// Round-6 change: HALVED block so TWO independent blocks co-reside per CU.
//   r5 evidence: 1 block/CU, barrier-locked phases -> all waves read LDS, then all MFMA
//   (serialized 1536+2062 cyc/K-tile -> MfmaUtil pinned 50%). Two co-resident blocks drift
//   anti-phase: one block's LDS/barrier phase overlaps the other's MFMA phase (m114).
// BM=128 batch x [4 gates x 32 o] (=128 "N"), BK=64, 256 threads (4 waves: 2M x 2N).
// Wave tile 64(M) x 64(N = 4 gates x 16 o). acc[4][4] f32x4 = 64 VGPR.
// LDS: 2 buffers x (A 128x64 + B 128x64 bf16) = 64 KiB -> 2 blocks/CU. XOR swizzle.
// Grid: natural 2D (bm inner-fast) - r5-verified for L3 residency (FETCH 426 MB).
// Iteration = 2 K-tiles, 8 phases; each phase: {4-8 ds_read | stage one 8KB half-tile
// (2 gload_lds) | barrier | lgkm0 | 8 MFMA | barrier}. vmcnt(6) only at P4/P8.
#define FENCE asm volatile("" ::: "memory")
#define BARRIER do { FENCE; __builtin_amdgcn_s_barrier(); FENCE; } while (0)
#define LGKM0 asm volatile("s_waitcnt lgkmcnt(0)" ::: "memory")
#define LGKM4 asm volatile("s_waitcnt lgkmcnt(4)" ::: "memory")
#define VMC6  asm volatile("s_waitcnt vmcnt(6)" ::: "memory")
#define VMC0  asm volatile("s_waitcnt vmcnt(0)" ::: "memory")

__global__ __launch_bounds__(256, 2) void lstm_gemm_kernel(
    const unsigned short* __restrict__ xb, const unsigned short* __restrict__ hb,
    const unsigned short* __restrict__ wit, const unsigned short* __restrict__ wht,
    const float* __restrict__ bi, const float* __restrict__ bh,
    const float* __restrict__ prev_c, float* __restrict__ out) {
  __shared__ char lds[65536];

  const int tid = threadIdx.x;
  const int wave = tid >> 6, lane = tid & 63;
  const int wm = wave >> 1, wn = wave & 1;
  const int bm = blockIdx.x;   // 0..63 (batch tile 128, inner-fast)
  const int bo = blockIdx.y;   // 0..63 (out-col tile 32)

  // --- fragment ds_read offsets (A region rows 0..127; B region rows = g*32+o_local) ---
  const int kwin = (lane >> 4) << 4;
  const int fswz = (lane & 7) << 4;
  int aro[4], bro[4];
#pragma unroll
  for (int mf = 0; mf < 4; ++mf) aro[mf] = (wm * 64 + mf * 16 + (lane & 15)) * 128;
#pragma unroll
  for (int nf = 0; nf < 4; ++nf) bro[nf] = 16384 + (nf * 32 + wn * 16 + (lane & 15)) * 128;

  // --- staging offsets (pre-swizzled global src, linear LDS dest; rule #21) ---
  const int L0 = tid * 16;
  int agoff[2][2], bgoff[2][2];
#pragma unroll
  for (int h = 0; h < 2; ++h)
#pragma unroll
    for (int j = 0; j < 2; ++j) {
      int L = j * 4096 + L0;                       // 0..8191 within 8KB half
      int grow = h * 64 + (L >> 7);                // 0..127
      int c = (L & 127) ^ ((grow & 7) << 4);
      agoff[h][j] = grow * 4096 + c;               // A row = batch row (stride 4096 B)
      bgoff[h][j] = (grow >> 5) * 8388608 + (grow & 31) * 4096 + c;  // g*8MB + o*4KB
    }
  const char* pxa = (const char*)xb + (size_t)bm * 524288;   // 128 rows * 4096 B
  const char* pha = (const char*)hb + (size_t)bm * 524288;
  const char* pwi = (const char*)wit + (size_t)bo * 131072;  // 32 o-rows * 4096 B
  const char* pwh = (const char*)wht + (size_t)bo * 131072;

  auto stageA = [&](int t, int h, int buf) {
    const char* base = (t < 32) ? (pxa + t * 128) : (pha + (t - 32) * 128);
    char* d = lds + buf * 32768 + h * 8192 + L0;
    async16(base + agoff[h][0], d);
    async16(base + agoff[h][1], d + 4096);
  };
  auto stageB = [&](int t, int h, int buf) {
    const char* base = (t < 32) ? (pwi + t * 128) : (pwh + (t - 32) * 128);
    char* d = lds + buf * 32768 + 16384 + h * 8192 + L0;
    async16(base + bgoff[h][0], d);
    async16(base + bgoff[h][1], d + 4096);
  };

  f32x4 acc[4][4];
  const f32x4 zero = {0.f, 0.f, 0.f, 0.f};
#pragma unroll
  for (int mf = 0; mf < 4; ++mf)
#pragma unroll
    for (int nf = 0; nf < 4; ++nf) acc[mf][nf] = zero;

  bf16x8 afr[2][2];   // one A half (2 mf), reused across nh
  bf16x8 bfr[4][2];   // all 4 gates live

  auto loadA = [&](int buf, int mh) {
    const char* l = lds + buf * 32768;
#pragma unroll
    for (int m = 0; m < 2; ++m)
#pragma unroll
      for (int ks = 0; ks < 2; ++ks)
        afr[m][ks] = *(const bf16x8*)(l + aro[mh * 2 + m] + ((ks * 64 + kwin) ^ fswz));
  };
  auto loadB = [&](int buf, int nh) {
    const char* l = lds + buf * 32768;
#pragma unroll
    for (int n = 0; n < 2; ++n)
#pragma unroll
      for (int ks = 0; ks < 2; ++ks)
        bfr[nh * 2 + n][ks] = *(const bf16x8*)(l + bro[nh * 2 + n] + ((ks * 64 + kwin) ^ fswz));
  };
  auto MF8 = [&](int mh, int nh) {
    __builtin_amdgcn_s_setprio(1);
#pragma unroll
    for (int ks = 0; ks < 2; ++ks)
#pragma unroll
      for (int n = 0; n < 2; ++n)
#pragma unroll
        for (int m = 0; m < 2; ++m)
          acc[mh * 2 + m][nh * 2 + n] = __builtin_amdgcn_mfma_f32_16x16x32_bf16(
              afr[m][ks], bfr[nh * 2 + n][ks], acc[mh * 2 + m][nh * 2 + n], 0, 0, 0);
    __builtin_amdgcn_s_setprio(0);
  };

  // --- prologue: t0 all 4 halves -> buf0; t1 {B0,B1,A0} -> buf1 ---
  stageB(0, 0, 0); stageB(0, 1, 0); stageA(0, 0, 0); stageA(0, 1, 0);
  stageB(1, 0, 1); stageB(1, 1, 1); stageA(1, 0, 1);
  VMC6;          // t0's 8 loads landed; t1's 6 still in flight
  BARRIER;

  // --- main loop: iterations 0..30, tiles t0=2i (buf0), t1=2i+1 (buf1) ---
  for (int i = 0; i < 31; ++i) {
    const int t1 = 2 * i + 1, t2 = 2 * i + 2, t3 = 2 * i + 3;
    // P1: Q00 of t0
    loadA(0, 0); loadB(0, 0); stageA(t1, 1, 1); LGKM4; BARRIER; LGKM0; MF8(0, 0); BARRIER;
    // P2: Q01
    loadB(0, 1); stageB(t2, 0, 0); BARRIER; LGKM0; MF8(0, 1); BARRIER;
    // P3: Q10
    loadA(0, 1); stageB(t2, 1, 0); BARRIER; LGKM0; MF8(1, 0); BARRIER;
    // P4: Q11 (regs only)
    stageA(t2, 0, 0); BARRIER; MF8(1, 1); VMC6; BARRIER;   // all of t1 landed
    // P5: Q00 of t1
    loadA(1, 0); loadB(1, 0); stageA(t2, 1, 0); LGKM4; BARRIER; LGKM0; MF8(0, 0); BARRIER;
    // P6: Q01
    loadB(1, 1); stageB(t3, 0, 1); BARRIER; LGKM0; MF8(0, 1); BARRIER;
    // P7: Q10
    loadA(1, 1); stageB(t3, 1, 1); BARRIER; LGKM0; MF8(1, 0); BARRIER;
    // P8: Q11
    stageA(t3, 0, 1); BARRIER; MF8(1, 1); VMC6; BARRIER;   // all of t2 landed
  }

  // --- epilogue iteration: tiles 62 (buf0), 63 (buf1); only stage = t63A1 ---
  loadA(0, 0); loadB(0, 0); stageA(63, 1, 1); LGKM4; BARRIER; LGKM0; MF8(0, 0); BARRIER;
  loadB(0, 1); BARRIER; LGKM0; MF8(0, 1); BARRIER;
  loadA(0, 1); BARRIER; LGKM0; MF8(1, 0); BARRIER;
  BARRIER; MF8(1, 1); VMC0; BARRIER;                        // t63 fully landed
  loadA(1, 0); loadB(1, 0); LGKM4; BARRIER; LGKM0; MF8(0, 0); BARRIER;
  loadB(1, 1); BARRIER; LGKM0; MF8(0, 1); BARRIER;
  loadA(1, 1); BARRIER; LGKM0; MF8(1, 0); BARRIER;
  MF8(1, 1);

  // --- LSTM cell epilogue (lane-local; C/D: col=lane&15, row=(lane>>4)*4+reg) ---
  const int col = lane & 15, rg = lane >> 4;
  const int o = bo * 32 + wn * 16 + col;
  float bs[4];
#pragma unroll
  for (int g = 0; g < 4; ++g) bs[g] = bi[g * 2048 + o] + bh[g * 2048 + o];
#pragma unroll
  for (int mf = 0; mf < 4; ++mf) {
    int bbase = bm * 128 + wm * 64 + mf * 16 + rg * 4;
#pragma unroll
    for (int r = 0; r < 4; ++r) {
      int b = bbase + r;
      float gi = sigm(acc[mf][0][r] + bs[0]);
      float gf = sigm(acc[mf][1][r] + bs[1]);
      float g2 = sigm(acc[mf][2][r] + bs[2]);
      float go = sigm(acc[mf][3][r] + bs[3]);
      float c = prev_c[(size_t)b * 2048 + o];
      float nc = gf * c + gi * g2;
      float e = __expf(2.f * nc);
      float nh = go + (e - 1.f) / (e + 1.f);   // faithful: out_gate + tanh(next_c)
      out[(size_t)b * 2048 + o] = nh;
      out[(size_t)HALF_OUT + (size_t)b * 2048 + o] = nc;
    }
  }
}

extern "C" void kernel_launch(void* const* d_in, const int* in_sizes, int n_in,
                              void* d_out, int out_size, void* d_ws, size_t ws_size,
                              hipStream_t stream) {
  const float* x  = (const float*)d_in[0];
  const float* ph = (const float*)d_in[1];
  const float* pc = (const float*)d_in[2];
  const float* Wi = (const float*)d_in[3];
  const float* Wh = (const float*)d_in[4];
  const float* bi = (const float*)d_in[5];
  const float* bh = (const float*)d_in[6];
  float* out = (float*)d_out;

  if (ws_size < (size_t)4 * SZ_ELEMS * sizeof(unsigned short)) return;
  unsigned short* xb  = (unsigned short*)d_ws;
  unsigned short* hb  = xb + SZ_ELEMS;
  unsigned short* wit = hb + SZ_ELEMS;
  unsigned short* wht = wit + SZ_ELEMS;

  cvt_bf16_kernel<<<2048, 256, 0, stream>>>(x, xb, 4194304);
  cvt_bf16_kernel<<<2048, 256, 0, stream>>>(ph, hb, 4194304);
  transpose_w_kernel<<<dim3(32, 32, 8), 256, 0, stream>>>(Wi, Wh, wit, wht);
  lstm_gemm_kernel<<<dim3(64, 64), 256, 0, stream>>>(xb, hb, wit, wht, bi, bh, pc, out);
}

// Round 7
// 510.656 us; speedup vs baseline: 1.1279x; 1.1279x over previous
//
#include <hip/hip_runtime.h>
#include <stdint.h>

// ---- Problem constants ----
// B=8192, IN=2048, OUT=2048, G=4.  K_total = 4096 (x-half then h-half).
// gates[b][g][o] = sum_k x[b][k]*Wi[g][k][o] + bi[g][o] + sum_k h[b][k]*Wh[g][k][o] + bh[g][o]
// next_c = sig(g1)*prev_c + sig(g0)*sig(g2);  next_h = sig(g3) + tanh(next_c)
// d_out = [next_h (8192*2048 f32)] ++ [next_c (8192*2048 f32)]

#define SZ_ELEMS 16777216
#define HALF_OUT 16777216

typedef __attribute__((ext_vector_type(8))) short bf16x8;
typedef __attribute__((ext_vector_type(4))) float f32x4;
typedef __attribute__((ext_vector_type(8))) unsigned short u16x8;

__device__ __forceinline__ unsigned short f2bf(float f) {
  unsigned int u = __float_as_uint(f);
  u += 0x7FFFu + ((u >> 16) & 1u);
  return (unsigned short)(u >> 16);
}

__device__ __forceinline__ void async16(const void* g, void* l) {
  __builtin_amdgcn_global_load_lds(
      (const __attribute__((address_space(1))) void*)g,
      (__attribute__((address_space(3))) void*)l, 16, 0, 0);
}

__device__ __forceinline__ float sigm(float x) { return 1.f / (1.f + __expf(-x)); }

// ---------------- f32 -> bf16 elementwise convert ----------------
__global__ void cvt_bf16_kernel(const float* __restrict__ src,
                                unsigned short* __restrict__ dst, int n4) {
  int i = blockIdx.x * blockDim.x + threadIdx.x;
  int stride = gridDim.x * blockDim.x;
  for (; i < n4; i += stride) {
    float4 v = reinterpret_cast<const float4*>(src)[i];
    ushort4 o;
    o.x = f2bf(v.x); o.y = f2bf(v.y); o.z = f2bf(v.z); o.w = f2bf(v.w);
    reinterpret_cast<ushort4*>(dst)[i] = o;
  }
}

// ---------------- W [g][k][o] f32  ->  Wt [g][o][k] bf16 ----------------
__global__ void transpose_w_kernel(const float* __restrict__ Wi, const float* __restrict__ Wh,
                                   unsigned short* __restrict__ Wit, unsigned short* __restrict__ Wht) {
  __shared__ float tile[64][65];
  const int tk = blockIdx.x, to = blockIdx.y, gz = blockIdx.z;
  const float* W = (gz < 4 ? Wi : Wh) + (size_t)(gz & 3) * 4194304;
  unsigned short* Wt = (gz < 4 ? Wit : Wht) + (size_t)(gz & 3) * 4194304;
  const int t = threadIdx.x;
  const int o = t & 63, kr = t >> 6;
#pragma unroll
  for (int p = 0; p < 16; ++p) {
    int k = p * 4 + kr;
    tile[k][o] = W[(size_t)(tk * 64 + k) * 2048 + to * 64 + o];
  }
  __syncthreads();
#pragma unroll
  for (int p = 0; p < 2; ++p) {
    int idx = p * 256 + t;
    int orow = idx >> 3, k0 = (idx & 7) * 8;
    u16x8 v;
#pragma unroll
    for (int i = 0; i < 8; ++i) v[i] = f2bf(tile[k0 + i][orow]);
    *reinterpret_cast<u16x8*>(&Wt[(size_t)(to * 64 + orow) * 2048 + tk * 64 + k0]) = v;
  }
}

// ---------------- fused GEMM (4 gates) + LSTM epilogue, 8-phase + frag prefetch ----------
// BM=256 batch x [4 gates x 64 o], BK=64, 512 threads (8 waves: 2M x 4N).
// Round-7 restructure: ONE barrier per phase; each phase's ds_reads are issued at the END
// of the PREVIOUS phase, so their latency hides under that phase's MFMA + barrier; the
// compiler's auto-waitcnt provides the counted lgkm wait before each MFMA (no inline lgkm).
// Phase p: { stage sigma(p); MFMA(frags[p]); [VMC6 @P4/P8 before reads]; reads(p+1); barrier }
// Ledger: every frag-read is consumed one phase after issue -> completion is barrier-proven
// before any stage overwrites its region (stages are >=2 phases after read-issue).
// VMC6 semantics unchanged: @P4 lands all t1, @P8 lands all t2 (3 half-tiles in flight).
#define FENCE asm volatile("" ::: "memory")
#define BARRIER do { FENCE; __builtin_amdgcn_s_barrier(); FENCE; } while (0)
#define VMC6  asm volatile("s_waitcnt vmcnt(6)" ::: "memory")
#define VMC0  asm volatile("s_waitcnt vmcnt(0)" ::: "memory")

__global__ __launch_bounds__(512, 2) void lstm_gemm_kernel(
    const unsigned short* __restrict__ xb, const unsigned short* __restrict__ hb,
    const unsigned short* __restrict__ wit, const unsigned short* __restrict__ wht,
    const float* __restrict__ bi, const float* __restrict__ bh,
    const float* __restrict__ prev_c, float* __restrict__ out) {
  __shared__ char lds[131072];

  const int tid = threadIdx.x;
  const int wave = tid >> 6, lane = tid & 63;
  const int wm = wave >> 2, wn = wave & 3;
  const int bm = blockIdx.x;   // 0..31 (batch tile, inner-fast) — r5-verified mapping
  const int bo = blockIdx.y;   // 0..31 (out-col tile)

  // --- fragment ds_read offsets ---
  const int kwin = (lane >> 4) << 4;
  const int fswz = (lane & 7) << 4;
  int aro[8], bro[4];
#pragma unroll
  for (int mf = 0; mf < 8; ++mf) aro[mf] = (wm * 128 + mf * 16 + (lane & 15)) * 128;
#pragma unroll
  for (int nf = 0; nf < 4; ++nf) bro[nf] = 32768 + (nf * 64 + wn * 16 + (lane & 15)) * 128;

  // --- staging offsets (pre-swizzled global src, linear LDS dest; rule #21) ---
  const int L0 = tid * 16;
  int agoff[2][2], bgoff[2][2];
#pragma unroll
  for (int h = 0; h < 2; ++h)
#pragma unroll
    for (int j = 0; j < 2; ++j) {
      int L = j * 8192 + L0;
      int row = h * 128 + (L >> 7);                // 0..255
      int c = (L & 127) ^ ((row & 7) << 4);
      agoff[h][j] = row * 4096 + c;                // A row = batch row
      int g = row >> 6, orow = row & 63;           // B row = g*64 + orow
      bgoff[h][j] = g * 8388608 + orow * 4096 + c;
    }
  const char* pxa = (const char*)xb + (size_t)bm * 1048576;
  const char* pha = (const char*)hb + (size_t)bm * 1048576;
  const char* pwi = (const char*)wit + (size_t)bo * 262144;
  const char* pwh = (const char*)wht + (size_t)bo * 262144;

  auto stageA = [&](int t, int h, int buf) {
    const char* base = (t < 32) ? (pxa + t * 128) : (pha + (t - 32) * 128);
    char* d = lds + buf * 65536 + h * 16384 + L0;
    async16(base + agoff[h][0], d);
    async16(base + agoff[h][1], d + 8192);
  };
  auto stageB = [&](int t, int h, int buf) {
    const char* base = (t < 32) ? (pwi + t * 128) : (pwh + (t - 32) * 128);
    char* d = lds + buf * 65536 + 32768 + h * 16384 + L0;
    async16(base + bgoff[h][0], d);
    async16(base + bgoff[h][1], d + 8192);
  };

  f32x4 acc[8][4];
  const f32x4 zero = {0.f, 0.f, 0.f, 0.f};
#pragma unroll
  for (int mf = 0; mf < 8; ++mf)
#pragma unroll
    for (int nf = 0; nf < 4; ++nf) acc[mf][nf] = zero;

  bf16x8 afrA[4][2];   // A frags, m-half 0 (rows wm*128 + 0..63)
  bf16x8 afrB[4][2];   // A frags, m-half 1 (rows wm*128 + 64..127)
  bf16x8 bfr[4][2];    // all 4 gate-fragments live

  auto loadAA = [&](int buf) {            // 8 ds_read_b128
    const char* l = lds + buf * 65536;
#pragma unroll
    for (int m = 0; m < 4; ++m)
#pragma unroll
      for (int ks = 0; ks < 2; ++ks)
        afrA[m][ks] = *(const bf16x8*)(l + aro[m] + ((ks * 64 + kwin) ^ fswz));
  };
  auto loadAB = [&](int buf) {            // 8 ds_read_b128
    const char* l = lds + buf * 65536;
#pragma unroll
    for (int m = 0; m < 4; ++m)
#pragma unroll
      for (int ks = 0; ks < 2; ++ks)
        afrB[m][ks] = *(const bf16x8*)(l + aro[4 + m] + ((ks * 64 + kwin) ^ fswz));
  };
  auto loadB0 = [&](int buf) {            // 4 ds_read_b128 (gates 0,1)
    const char* l = lds + buf * 65536;
#pragma unroll
    for (int n = 0; n < 2; ++n)
#pragma unroll
      for (int ks = 0; ks < 2; ++ks)
        bfr[n][ks] = *(const bf16x8*)(l + bro[n] + ((ks * 64 + kwin) ^ fswz));
  };
  auto loadB1 = [&](int buf) {            // 4 ds_read_b128 (gates 2,3)
    const char* l = lds + buf * 65536;
#pragma unroll
    for (int n = 0; n < 2; ++n)
#pragma unroll
      for (int ks = 0; ks < 2; ++ks)
        bfr[2 + n][ks] = *(const bf16x8*)(l + bro[2 + n] + ((ks * 64 + kwin) ^ fswz));
  };
  auto MQ = [&](int mh, int nh) {         // 16 MFMA: quadrant (mh, nh)
    __builtin_amdgcn_s_setprio(1);
#pragma unroll
    for (int ks = 0; ks < 2; ++ks)
#pragma unroll
      for (int n = 0; n < 2; ++n)
#pragma unroll
        for (int m = 0; m < 4; ++m)
          acc[mh * 4 + m][nh * 2 + n] = __builtin_amdgcn_mfma_f32_16x16x32_bf16(
              (mh ? afrB : afrA)[m][ks], bfr[nh * 2 + n][ks],
              acc[mh * 4 + m][nh * 2 + n], 0, 0, 0);
    __builtin_amdgcn_s_setprio(0);
  };

  // --- prologue: t0 all 4 halves -> buf0; t1 {B0,B1,A0} -> buf1; prime Q00 frags ---
  stageB(0, 0, 0); stageB(0, 1, 0); stageA(0, 0, 0); stageA(0, 1, 0);
  stageB(1, 0, 1); stageB(1, 1, 1); stageA(1, 0, 1);
  VMC6;                 // t0's 8 loads landed; t1's 6 still in flight
  BARRIER;
  loadAA(0); loadB0(0); // Q00(t0) fragments — consumed in P1

  // --- main loop: iterations 0..30, tiles t0=2i (buf0), t1=2i+1 (buf1) ---
  for (int i = 0; i < 31; ++i) {
    const int t1 = 2 * i + 1, t2 = 2 * i + 2, t3 = 2 * i + 3;
    // P1: Q00(t0); prefetch bfr1[buf0]
    stageA(t1, 1, 1); MQ(0, 0); loadB1(0); BARRIER;
    // P2: Q01(t0); prefetch afrB[buf0]
    stageB(t2, 0, 0); MQ(0, 1); loadAB(0); BARRIER;
    // P3: Q10(t0)
    stageB(t2, 1, 0); MQ(1, 0); BARRIER;
    // P4: Q11(t0); all t1 landed; prefetch Q00(t1) frags
    stageA(t2, 0, 0); MQ(1, 1); VMC6; loadAA(1); loadB0(1); BARRIER;
    // P5: Q00(t1); prefetch bfr1[buf1]
    stageA(t2, 1, 0); MQ(0, 0); loadB1(1); BARRIER;
    // P6: Q01(t1); prefetch afrB[buf1]
    stageB(t3, 0, 1); MQ(0, 1); loadAB(1); BARRIER;
    // P7: Q10(t1)
    stageB(t3, 1, 1); MQ(1, 0); BARRIER;
    // P8: Q11(t1); all t2 landed; prefetch Q00(t2) frags
    stageA(t3, 0, 1); MQ(1, 1); VMC6; loadAA(0); loadB0(0); BARRIER;
  }

  // --- epilogue iteration: tiles 62 (buf0), 63 (buf1); only stage = t63A1 ---
  stageA(63, 1, 1); MQ(0, 0); loadB1(0); BARRIER;
  MQ(0, 1); loadAB(0); BARRIER;
  MQ(1, 0); BARRIER;
  MQ(1, 1); VMC0; loadAA(1); loadB0(1); BARRIER;    // t63 fully landed
  MQ(0, 0); loadB1(1); BARRIER;
  MQ(0, 1); loadAB(1); BARRIER;
  MQ(1, 0); BARRIER;
  MQ(1, 1);

  // --- LSTM cell epilogue (lane-local; C/D: col=lane&15, row=(lane>>4)*4+reg) ---
  const int col = lane & 15, rg = lane >> 4;
  const int o = bo * 64 + wn * 16 + col;
  float bs[4];
#pragma unroll
  for (int g = 0; g < 4; ++g) bs[g] = bi[g * 2048 + o] + bh[g * 2048 + o];
#pragma unroll
  for (int mf = 0; mf < 8; ++mf) {
    int bbase = bm * 256 + wm * 128 + mf * 16 + rg * 4;
#pragma unroll
    for (int r = 0; r < 4; ++r) {
      int b = bbase + r;
      float gi = sigm(acc[mf][0][r] + bs[0]);
      float gf = sigm(acc[mf][1][r] + bs[1]);
      float g2 = sigm(acc[mf][2][r] + bs[2]);
      float go = sigm(acc[mf][3][r] + bs[3]);
      float c = prev_c[(size_t)b * 2048 + o];
      float nc = gf * c + gi * g2;
      float e = __expf(2.f * nc);
      float nh = go + (e - 1.f) / (e + 1.f);   // faithful: out_gate + tanh(next_c)
      out[(size_t)b * 2048 + o] = nh;
      out[(size_t)HALF_OUT + (size_t)b * 2048 + o] = nc;
    }
  }
}

extern "C" void kernel_launch(void* const* d_in, const int* in_sizes, int n_in,
                              void* d_out, int out_size, void* d_ws, size_t ws_size,
                              hipStream_t stream) {
  const float* x  = (const float*)d_in[0];
  const float* ph = (const float*)d_in[1];
  const float* pc = (const float*)d_in[2];
  const float* Wi = (const float*)d_in[3];
  const float* Wh = (const float*)d_in[4];
  const float* bi = (const float*)d_in[5];
  const float* bh = (const float*)d_in[6];
  float* out = (float*)d_out;

  if (ws_size < (size_t)4 * SZ_ELEMS * sizeof(unsigned short)) return;
  unsigned short* xb  = (unsigned short*)d_ws;
  unsigned short* hb  = xb + SZ_ELEMS;
  unsigned short* wit = hb + SZ_ELEMS;
  unsigned short* wht = wit + SZ_ELEMS;

  cvt_bf16_kernel<<<2048, 256, 0, stream>>>(x, xb, 4194304);
  cvt_bf16_kernel<<<2048, 256, 0, stream>>>(ph, hb, 4194304);
  transpose_w_kernel<<<dim3(32, 32, 8), 256, 0, stream>>>(Wi, Wh, wit, wht);
  lstm_gemm_kernel<<<dim3(32, 32), 512, 0, stream>>>(xb, hb, wit, wht, bi, bh, pc, out);
}